// Round 6
// baseline (75.695 us; speedup 1.0000x reference)
//
#include <hip/hip_runtime.h>
#include <math.h>

#define LOG2E 1.4426950408889634f
#define LN2   0.6931471805599453f

static constexpr int M = 1024;
static constexpr int N = 65536;

__device__ inline float wave_max64(float v) {
    #pragma unroll
    for (int o = 32; o > 0; o >>= 1) v = fmaxf(v, __shfl_xor(v, o));
    return v;
}
__device__ inline float wave_sum64(float v) {
    #pragma unroll
    for (int o = 32; o > 0; o >>= 1) v += __shfl_xor(v, o);
    return v;
}

// Single fused kernel: 256 blocks x 1024 threads (16 waves), 1 block/CU.
// Log-domain math in base-2 throughout (v_exp_f32/v_log_f32 are 2^x/log2 x):
//   t2_j  = w_j*LOG2E + 0.5*log2(det_j)
//   maxt2 = max_j t2_j                      (single pre-phase-2 max reduction)
//   c0_j  = t2_j - maxt2 - mGm_j*LOG2E     (softmax lse cancels here)
//   out_i = LN2 * (maxt2 - lse2 + log2 sum_j 2^{v2_ij})
// Phase 2: 16 waves split M 16-way; S=4 samples/lane; component pairs fetched
// as 3x ds_read_b128 (stride-6 packing); loop software-pipelined: next pair's
// loads issued before current pair's 56-cycle FMA/exp block.
__global__ __launch_bounds__(1024)
void gm_all(const float* __restrict__ sample,
            const float* __restrict__ mu,
            const float* __restrict__ A,
            const float* __restrict__ w,
            float* __restrict__ out) {
    __shared__ __align__(16) float coef[M*6];     // 24 KiB
    __shared__ float partial[16*256];             // 16 KiB
    __shared__ float redA[16];
    __shared__ float redB[16];

    const int t    = threadIdx.x;
    const int lane = t & 63;
    const int wv   = t >> 6;                      // 0..15
    const int base = blockIdx.x * 256;

    // sample loads issued first (overlap with prep)
    float x0[4], x1[4];
    #pragma unroll
    for (int k = 0; k < 4; k++) {
        const float2 p = ((const float2*)sample)[base + 64*k + lane];
        x0[k] = p.x; x1[k] = p.y;
    }

    // ---- prep: component j = t ----
    const float4 a = ((const float4*)A)[t];       // A00,A01,A10,A11
    const float g00 = a.x*a.x + a.y*a.y;
    const float g01 = a.x*a.z + a.y*a.w;
    const float g11 = a.z*a.z + a.w*a.w;
    const float2 m  = ((const float2*)mu)[t];
    const float gm0 = g00*m.x + g01*m.y;
    const float gm1 = g01*m.x + g11*m.y;
    const float mGm = gm0*m.x + gm1*m.y;
    const float det = g00*g11 - g01*g01;

    const float w2 = w[t] * LOG2E;
    const float t2 = w2 + 0.5f * __builtin_amdgcn_logf(det);

    // joint block-max of (w2, t2): one barrier phase
    float mw = wave_max64(w2);
    float mt = wave_max64(t2);
    if (lane == 0) { redA[wv] = mw; redB[wv] = mt; }
    __syncthreads();
    float wmax2 = redA[0], maxt2 = redB[0];
    #pragma unroll
    for (int i = 1; i < 16; i++) {
        wmax2 = fmaxf(wmax2, redA[i]);
        maxt2 = fmaxf(maxt2, redB[i]);
    }

    {
        float* c = coef + t*6;
        c[0] = t2 - maxt2 - LOG2E * mGm;
        c[1] = LOG2E * 2.0f * gm0;
        c[2] = LOG2E * 2.0f * gm1;
        c[3] = -LOG2E * g00;
        c[4] = -LOG2E * 2.0f * g01;
        c[5] = -LOG2E * g11;
    }
    __syncthreads();

    // block-sum of 2^(w2-wmax2) -> lse2 (consumed only in epilogue, after
    // the next __syncthreads; no barrier needed here)
    float sw = wave_sum64(__builtin_amdgcn_exp2f(w2 - wmax2));
    if (lane == 0) redA[wv] = sw;

    // ---- phase 2 ----
    const float xx[4] = {x0[0]*x0[0], x0[1]*x0[1], x0[2]*x0[2], x0[3]*x0[3]};
    const float xy[4] = {x0[0]*x1[0], x0[1]*x1[1], x0[2]*x1[2], x0[3]*x1[3]};
    const float yy[4] = {x1[0]*x1[0], x1[1]*x1[1], x1[2]*x1[2], x1[3]*x1[3]};
    float accA[4] = {0.0f, 0.0f, 0.0f, 0.0f};
    float accB[4] = {0.0f, 0.0f, 0.0f, 0.0f};

    const float4* cw = (const float4*)(coef + wv*64*6);

    // software pipeline: preload pair jj+1 while computing pair jj
    float4 q0 = cw[0], q1 = cw[1], q2 = cw[2];
    #pragma unroll 4
    for (int jj = 0; jj < 32; jj++) {
        float4 n0, n1, n2;
        if (jj < 31) {
            n0 = cw[(jj+1)*3 + 0];
            n1 = cw[(jj+1)*3 + 1];
            n2 = cw[(jj+1)*3 + 2];
        }
        #pragma unroll
        for (int k = 0; k < 4; k++) {
            const float va = fmaf(q1.y, yy[k], fmaf(q1.x, xy[k],
                             fmaf(q0.w, xx[k], fmaf(q0.z, x1[k],
                             fmaf(q0.y, x0[k], q0.x)))));
            const float vb = fmaf(q2.w, yy[k], fmaf(q2.z, xy[k],
                             fmaf(q2.y, xx[k], fmaf(q2.x, x1[k],
                             fmaf(q1.w, x0[k], q1.z)))));
            accA[k] += __builtin_amdgcn_exp2f(va);
            accB[k] += __builtin_amdgcn_exp2f(vb);
        }
        if (jj < 31) { q0 = n0; q1 = n1; q2 = n2; }
    }

    #pragma unroll
    for (int k = 0; k < 4; k++)
        partial[wv*256 + 64*k + lane] = accA[k] + accB[k];
    __syncthreads();

    if (t < 256) {
        float s = 0.0f;
        #pragma unroll
        for (int w2i = 0; w2i < 16; w2i++) s += partial[w2i*256 + t];
        float se = 0.0f;
        #pragma unroll
        for (int i = 0; i < 16; i++) se += redA[i];
        const float lse2 = wmax2 + __builtin_amdgcn_logf(se);
        out[base + t] = LN2 * (maxt2 - lse2 + __builtin_amdgcn_logf(s));
    }
}

extern "C" void kernel_launch(void* const* d_in, const int* in_sizes, int n_in,
                              void* d_out, int out_size, void* d_ws, size_t ws_size,
                              hipStream_t stream) {
    const float* sample = (const float*)d_in[0];
    const float* mu     = (const float*)d_in[1];
    const float* A      = (const float*)d_in[2];
    const float* w      = (const float*)d_in[3];
    float* out = (float*)d_out;
    (void)d_ws; (void)ws_size;

    gm_all<<<N/256, 1024, 0, stream>>>(sample, mu, A, w, out);
}

// Round 7
// 73.368 us; speedup vs baseline: 1.0317x; 1.0317x over previous
//
#include <hip/hip_runtime.h>
#include <math.h>

#define LOG2E 1.4426950408889634f
#define LN2   0.6931471805599453f

static constexpr int M = 1024;
static constexpr int N = 65536;

__device__ inline float wave_max64(float v) {
    #pragma unroll
    for (int o = 32; o > 0; o >>= 1) v = fmaxf(v, __shfl_xor(v, o));
    return v;
}
__device__ inline float wave_sum64(float v) {
    #pragma unroll
    for (int o = 32; o > 0; o >>= 1) v += __shfl_xor(v, o);
    return v;
}

// Single fused kernel: 256 blocks x 1024 threads (16 waves), 1 block/CU.
// All log-domain math in base-2 (v_exp_f32 / v_log_f32 are 2^x / log2 x).
//   t2_j  = w_j*LOG2E + 0.5*log2(det_j)
//   maxt2 = max_j t2_j                      (ONE pre-phase-2 max reduction)
//   c0_j  = t2_j - maxt2 - mGm_j*LOG2E     (lse cancels here!)
//   v2_ij = c0_j + linear/quadratic terms  (<= 0 by construction)
//   out_i = LN2 * (maxt2 - lse2 + log2 sum_j 2^{v2_ij})
//   lse2  = wmax2 + log2 sum_j 2^{w2_j - wmax2}   (only needed in epilogue)
// NOTE: R6 tried source-level SW pipelining of the hot loop -> +2.6us
// regression (VGPR pressure + loop-guard overhead; compiler scheduling was
// already near-optimal). This is the R5 structure, the measured optimum.
__global__ __launch_bounds__(1024)
void gm_all(const float* __restrict__ sample,
            const float* __restrict__ mu,
            const float* __restrict__ A,
            const float* __restrict__ w,
            float* __restrict__ out) {
    __shared__ __align__(16) float coef[M*6];     // 24 KiB, stride 6
    __shared__ float partial[16*256];             // 16 KiB
    __shared__ float redA[16];
    __shared__ float redB[16];

    const int t    = threadIdx.x;
    const int lane = t & 63;
    const int wv   = t >> 6;                      // 0..15
    const int base = blockIdx.x * 256;

    // ---- sample loads issued first (overlap with prep) ----
    float x0[4], x1[4];
    #pragma unroll
    for (int k = 0; k < 4; k++) {
        const float2 p = ((const float2*)sample)[base + 64*k + lane];
        x0[k] = p.x; x1[k] = p.y;
    }

    // ---- prep: component j = t ----
    const float4 a = ((const float4*)A)[t];       // A00,A01,A10,A11
    const float g00 = a.x*a.x + a.y*a.y;
    const float g01 = a.x*a.z + a.y*a.w;
    const float g11 = a.z*a.z + a.w*a.w;
    const float2 m  = ((const float2*)mu)[t];
    const float gm0 = g00*m.x + g01*m.y;
    const float gm1 = g01*m.x + g11*m.y;
    const float mGm = gm0*m.x + gm1*m.y;
    const float det = g00*g11 - g01*g01;

    const float w2 = w[t] * LOG2E;                           // log2-domain w
    const float t2 = w2 + 0.5f * __builtin_amdgcn_logf(det); // + 0.5*log2(det)

    // joint block-max of (w2, t2): one barrier phase
    float mw = wave_max64(w2);
    float mt = wave_max64(t2);
    if (lane == 0) { redA[wv] = mw; redB[wv] = mt; }
    __syncthreads();
    float wmax2 = redA[0], maxt2 = redB[0];
    #pragma unroll
    for (int i = 1; i < 16; i++) {
        wmax2 = fmaxf(wmax2, redA[i]);
        maxt2 = fmaxf(maxt2, redB[i]);
    }

    // coefficients (phase 2 starts right after the next barrier)
    {
        float* c = coef + t*6;
        c[0] = t2 - maxt2 - LOG2E * mGm;
        c[1] = LOG2E * 2.0f * gm0;
        c[2] = LOG2E * 2.0f * gm1;
        c[3] = -LOG2E * g00;
        c[4] = -LOG2E * 2.0f * g01;
        c[5] = -LOG2E * g11;
    }
    __syncthreads();

    // block-sum of 2^(w2 - wmax2) -> lse2 (consumed only in epilogue, after
    // the next __syncthreads; no barrier needed here)
    float sw = wave_sum64(__builtin_amdgcn_exp2f(w2 - wmax2));
    if (lane == 0) redA[wv] = sw;

    // ---- phase 2: 16 waves split M 16-way, S=4 samples/lane ----
    const float xx[4] = {x0[0]*x0[0], x0[1]*x0[1], x0[2]*x0[2], x0[3]*x0[3]};
    const float xy[4] = {x0[0]*x1[0], x0[1]*x1[1], x0[2]*x1[2], x0[3]*x1[3]};
    const float yy[4] = {x1[0]*x1[0], x1[1]*x1[1], x1[2]*x1[2], x1[3]*x1[3]};
    float accA[4] = {0.0f, 0.0f, 0.0f, 0.0f};
    float accB[4] = {0.0f, 0.0f, 0.0f, 0.0f};

    // wave wv owns components [wv*64, wv*64+64) in pairs: 3x ds_read_b128.
    const float4* cw = (const float4*)(coef + wv*64*6);
    #pragma unroll 8
    for (int jj = 0; jj < 32; jj++) {
        const float4 q0 = cw[jj*3 + 0];   // c0a c1a c2a c3a
        const float4 q1 = cw[jj*3 + 1];   // c4a c5a c0b c1b
        const float4 q2 = cw[jj*3 + 2];   // c2b c3b c4b c5b
        #pragma unroll
        for (int k = 0; k < 4; k++) {
            const float va = fmaf(q1.y, yy[k], fmaf(q1.x, xy[k],
                             fmaf(q0.w, xx[k], fmaf(q0.z, x1[k],
                             fmaf(q0.y, x0[k], q0.x)))));
            const float vb = fmaf(q2.w, yy[k], fmaf(q2.z, xy[k],
                             fmaf(q2.y, xx[k], fmaf(q2.x, x1[k],
                             fmaf(q1.w, x0[k], q1.z)))));
            accA[k] += __builtin_amdgcn_exp2f(va);
            accB[k] += __builtin_amdgcn_exp2f(vb);
        }
    }

    #pragma unroll
    for (int k = 0; k < 4; k++)
        partial[wv*256 + 64*k + lane] = accA[k] + accB[k];
    __syncthreads();

    if (t < 256) {
        float s = 0.0f;
        #pragma unroll
        for (int w2i = 0; w2i < 16; w2i++) s += partial[w2i*256 + t];
        float se = 0.0f;
        #pragma unroll
        for (int i = 0; i < 16; i++) se += redA[i];
        const float lse2 = wmax2 + __builtin_amdgcn_logf(se);
        out[base + t] = LN2 * (maxt2 - lse2 + __builtin_amdgcn_logf(s));
    }
}

extern "C" void kernel_launch(void* const* d_in, const int* in_sizes, int n_in,
                              void* d_out, int out_size, void* d_ws, size_t ws_size,
                              hipStream_t stream) {
    const float* sample = (const float*)d_in[0];
    const float* mu     = (const float*)d_in[1];
    const float* A      = (const float*)d_in[2];
    const float* w      = (const float*)d_in[3];
    float* out = (float*)d_out;
    (void)d_ws; (void)ws_size;

    gm_all<<<N/256, 1024, 0, stream>>>(sample, mu, A, w, out);
}